// Round 8
// baseline (558.622 us; speedup 1.0000x reference)
//
#include <hip/hip_runtime.h>

// GraphAttn: B=8,N=1024,C=64,F=32,O=128,D=O*F=4096, M=B*N=8192 rows.
// a[b,i,j]=leaky(a1_i+a2_j) is rank-1 pre-nonlinearity -> softmax(dim=i)+einsum
// collapses to sorted prefix/suffix sums. h2 never materialized (a2 = n.W2eff),
// a1 = x.W1eff (same identity). Conv = split-bf16 MFMA implicit GEMM writing h1
// in sorted-j order; segment sums fused into conv via atomics; final sweep is
// segment-parallel streaming.
// R7: conv 8 rows/block (4 blocks/CU, was latency-bound at 17.7% occupancy);
//     sortprep rank-by-counting (6 barriers, was ~75-barrier bitonic).

#define ALPHA 0.2f
typedef __attribute__((ext_vector_type(8))) short short8;
typedef __attribute__((ext_vector_type(4))) float f32x4;

constexpr int Bb = 8, Nn = 1024, Cc = 64, Ff = 32, Oo = 128, Dd = 4096, Mm = 8192;

__device__ __forceinline__ unsigned short f2bf(float v) {
  unsigned int u = __float_as_uint(v);
  unsigned int r = (u + 0x7FFFu + ((u >> 16) & 1u)) >> 16;
  return (unsigned short)r;
}
__device__ __forceinline__ float bf2f(unsigned short h) {
  return __uint_as_float(((unsigned int)h) << 16);
}

// ---------------- prep: B-fragments (hi/lo bf16), W1eff, W2eff, c1, c2 -------
__global__ __launch_bounds__(256) void prep_kernel(
    const float* __restrict__ w, const float* __restrict__ bias,
    const float* __restrict__ att1w, const float* __restrict__ att2w,
    unsigned short* __restrict__ Bph, unsigned short* __restrict__ Bpl,
    float* __restrict__ W1, float* __restrict__ W2, float* __restrict__ c12) {
  const int tid = threadIdx.x;
  const int gid = blockIdx.x * 256 + tid;
  for (int e = gid; e < 6 * 8 * 64 * 8; e += 64 * 256) {
    int j = e & 7, l = (e >> 3) & 63, ot = (e >> 9) & 7, kc = e >> 12;
    int kn = kc * 32 + ((l >> 4) << 3) + j;
    int c = kn & 63, k = kn >> 6;
    int o = ot * 16 + (l & 15);
    float v = w[o * 192 + c * 3 + k];
    unsigned short hi = f2bf(v);
    Bph[e] = hi;
    Bpl[e] = f2bf(v - bf2f(hi));
  }
  if (gid < 4096) {
    int which = gid >> 11;
    int e = gid & 2047;
    int c = e >> 5, g = e & 31;
    const float* aw = which ? att2w : att1w;
    float s = 0.f;
    for (int o = 0; o < 128; ++o) {
      const float* wp = w + o * 192 + c * 3;
      const float* ap = aw + o * 32;
#pragma unroll
      for (int k = 0; k < 3; ++k) s += wp[k] * ap[(g - k + 1 + 32) & 31];
    }
    (which ? W2 : W1)[e] = s;
  }
  if (blockIdx.x == 63) {
    __shared__ float red[256];
    int o = tid & 127;
    const float* aw = (tid < 128) ? att1w : att2w;
    float t = 0.f;
    for (int f = 0; f < 32; ++f) t += aw[o * 32 + f];
    red[tid] = t * bias[o];
    __syncthreads();
    for (int st = 64; st >= 1; st >>= 1) {
      if ((tid & 127) < st) red[tid] += red[tid + st];
      __syncthreads();
    }
    if (tid == 0) c12[0] = red[0];
    if (tid == 128) c12[1] = red[128];
  }
}

// ---------------- a1 = x.W1+c1, a2 = n.W2+c2; also zero segsum ----------------
__global__ __launch_bounds__(256) void a12_kernel(
    const float* __restrict__ x, const float* __restrict__ n,
    const float* __restrict__ W1, const float* __restrict__ W2,
    const float* __restrict__ c12, float* __restrict__ a1,
    float* __restrict__ a2, float* __restrict__ segsum) {
  const int tid = threadIdx.x, lane = tid & 63, wv = tid >> 6;
  const int gid = blockIdx.x * 256 + tid;
  segsum[(size_t)gid * 2] = 0.f;
  segsum[(size_t)gid * 2 + 1] = 0.f;
  float4 w1r[8], w2r[8];
#pragma unroll
  for (int q = 0; q < 8; ++q) {
    w1r[q] = *reinterpret_cast<const float4*>(W1 + q * 256 + lane * 4);
    w2r[q] = *reinterpret_cast<const float4*>(W2 + q * 256 + lane * 4);
  }
  const float c1 = c12[0], c2v = c12[1];
  const int gw = blockIdx.x * 4 + wv;
#pragma unroll
  for (int rr = 0; rr < 2; ++rr) {
    int m = gw * 2 + rr;
    const float* xp = x + (size_t)m * 2048;
    const float* np = n + (size_t)m * 2048;
    float s1 = 0.f, s2 = 0.f;
#pragma unroll
    for (int q = 0; q < 8; ++q) {
      float4 xv = *reinterpret_cast<const float4*>(xp + q * 256 + lane * 4);
      float4 nv = *reinterpret_cast<const float4*>(np + q * 256 + lane * 4);
      s1 += w1r[q].x * xv.x + w1r[q].y * xv.y + w1r[q].z * xv.z + w1r[q].w * xv.w;
      s2 += w2r[q].x * nv.x + w2r[q].y * nv.y + w2r[q].z * nv.z + w2r[q].w * nv.w;
    }
#pragma unroll
    for (int d = 1; d < 64; d <<= 1) {
      s1 += __shfl_xor(s1, d);
      s2 += __shfl_xor(s2, d);
    }
    if (lane == 0) { a1[m] = s1 + c1; a2[m] = s2 + c2v; }
  }
}

// ---------------- per-batch rank-sort + softmax factor prep ------------------
// Rank-by-counting (stable, tie-break by index -> exact permutation, same
// ordering as a stable sort). ~6 barriers total vs ~75 for bitonic+scan.
__global__ __launch_bounds__(1024) void sortprep_kernel(
    const float* __restrict__ a1, const float* __restrict__ a2,
    float* __restrict__ jsu, float* __restrict__ jsv, int* __restrict__ jrow,
    int* __restrict__ isrow, int* __restrict__ isk,
    float* __restrict__ isep, float* __restrict__ isea) {
  __shared__ __align__(16) float A1[1024];
  __shared__ __align__(16) float A2[1024];
  __shared__ float k1[1024]; __shared__ int x1[1024];
  __shared__ float k2[1024]; __shared__ int x2[1024];
  __shared__ float p1[1024]; __shared__ float q1[1024];
  __shared__ float wp[16]; __shared__ float wq[16];
  const int tid = threadIdx.x;
  const int lane = tid & 63, wv = tid >> 6;
  const int b = blockIdx.x;
  const float v1 = a1[b * 1024 + tid];
  const float v2 = a2[b * 1024 + tid];
  A1[tid] = v1; A2[tid] = v2;
  __syncthreads();
  int r1 = 0, r2 = 0;
  for (int j = 0; j < 1024; j += 4) {
    float4 c1 = *reinterpret_cast<const float4*>(&A1[j]);
    float4 c2 = *reinterpret_cast<const float4*>(&A2[j]);
    r1 += (c1.x < v1 || (c1.x == v1 && j + 0 < tid)) ? 1 : 0;
    r1 += (c1.y < v1 || (c1.y == v1 && j + 1 < tid)) ? 1 : 0;
    r1 += (c1.z < v1 || (c1.z == v1 && j + 2 < tid)) ? 1 : 0;
    r1 += (c1.w < v1 || (c1.w == v1 && j + 3 < tid)) ? 1 : 0;
    r2 += (c2.x < v2 || (c2.x == v2 && j + 0 < tid)) ? 1 : 0;
    r2 += (c2.y < v2 || (c2.y == v2 && j + 1 < tid)) ? 1 : 0;
    r2 += (c2.z < v2 || (c2.z == v2 && j + 2 < tid)) ? 1 : 0;
    r2 += (c2.w < v2 || (c2.w == v2 && j + 3 < tid)) ? 1 : 0;
  }
  k1[r1] = v1; x1[r1] = tid;   // ranks form a permutation -> no collisions
  k2[r2] = v2; x2[r2] = tid;
  __syncthreads();
  // inclusive scans of exp(k1), exp(alpha*k1): wave shfl-scan + 16 partials
  float pv = expf(k1[tid]);
  float qv = expf(ALPHA * k1[tid]);
#pragma unroll
  for (int off = 1; off < 64; off <<= 1) {
    float tp = __shfl_up(pv, off);
    float tq = __shfl_up(qv, off);
    if (lane >= off) { pv += tp; qv += tq; }
  }
  if (lane == 63) { wp[wv] = pv; wq[wv] = qv; }
  __syncthreads();
  if (tid == 0) {
    float sp = 0.f, sq = 0.f;
#pragma unroll
    for (int i = 0; i < 16; ++i) { sp += wp[i]; wp[i] = sp; sq += wq[i]; wq[i] = sq; }
  }
  __syncthreads();
  if (wv > 0) { pv += wp[wv - 1]; qv += wq[wv - 1]; }
  p1[tid] = pv; q1[tid] = qv;
  __syncthreads();
  const float Ptot = p1[1023];
  {
    float a2v = k2[tid];
    float thr = -a2v;
    int lo = 0, hi = 1024;
    while (lo < hi) { int mid = (lo + hi) >> 1; if (k1[mid] < thr) lo = mid + 1; else hi = mid; }
    float Psuf = Ptot - (lo ? p1[lo - 1] : 0.f);
    float Qpre = lo ? q1[lo - 1] : 0.f;
    float eb = expf(a2v), ea = expf(ALPHA * a2v);
    float den = eb * Psuf + ea * Qpre;
    jsu[b * 1024 + tid] = eb / den;
    jsv[b * 1024 + tid] = ea / den;
    jrow[b * 1024 + tid] = b * 1024 + x2[tid];
  }
  {
    float a1v = k1[tid];
    float thr = -a1v;
    int lo = 0, hi = 1024;
    while (lo < hi) { int mid = (lo + hi) >> 1; if (k2[mid] < thr) lo = mid + 1; else hi = mid; }
    int s = 1023 - tid;
    isrow[b * 1024 + s] = b * 1024 + x1[tid];
    isk[b * 1024 + s] = lo;
    isep[b * 1024 + s] = expf(a1v);
    isea[b * 1024 + s] = expf(ALPHA * a1v);
  }
}

// ---------------- conv: split-bf16 MFMA, writes h1 in sorted-j order ---------
// R7: 8 rows/block, grid 1024, 4 blocks/CU (16 waves) — was 2 blocks/CU and
// latency-bound (MfmaUtil 16%, VALUBusy 10%, occupancy 17.7%).
__global__ __launch_bounds__(256, 4) void conv_kernel(
    const float* __restrict__ x,
    const unsigned short* __restrict__ Bph, const unsigned short* __restrict__ Bpl,
    const float* __restrict__ bias,
    const int* __restrict__ jrow, const float* __restrict__ jsu,
    const float* __restrict__ jsv,
    float* __restrict__ h1s, float* __restrict__ segsum) {
  __shared__ unsigned char xsraw[16384];  // [2 buf][2 part][32 f][64 c] bf16
  const int tid = threadIdx.x, lane = tid & 63, wv = tid >> 6;
  const int s0 = blockIdx.x * 8;

  short8 bh[6][2], bl[6][2];
#pragma unroll
  for (int kc = 0; kc < 6; ++kc)
#pragma unroll
    for (int t2 = 0; t2 < 2; ++t2) {
      int ot = wv * 2 + t2;
      size_t idx = ((size_t)(kc * 8 + ot) * 64 + lane) * 8;
      bh[kc][t2] = *reinterpret_cast<const short8*>(Bph + idx);
      bl[kc][t2] = *reinterpret_cast<const short8*>(Bpl + idx);
    }
  float biasv[2];
  biasv[0] = bias[(wv * 2 + 0) * 16 + (lane & 15)];
  biasv[1] = bias[(wv * 2 + 1) * 16 + (lane & 15)];

  int offs[2][6];
#pragma unroll
  for (int ft = 0; ft < 2; ++ft)
#pragma unroll
    for (int kc = 0; kc < 6; ++kc) {
      int fo = ft * 16 + (lane & 15);
      int kb = kc * 32 + ((lane >> 4) << 3);
      int k = kb >> 6, c0 = kb & 63;
      int fx = (fo + k + 31) & 31;  // (fo + k - 1) mod 32
      int bo = (fx << 7) + (c0 << 1);
      offs[ft][kc] = bo ^ ((fx & 7) << 4);
    }

  float Uacc[2][2][4] = {{{0.f}}};
  float Vacc[2][2][4] = {{{0.f}}};
  const int cpair = tid & 31, fq = tid >> 5;

  auto stage = [&](int r, int bf) {
    int m = jrow[s0 + r];
    const float* xr = x + (size_t)m * 2048;
    int c = cpair * 2;
    float4 v0 = *reinterpret_cast<const float4*>(xr + c * 32 + fq * 4);
    float4 v1 = *reinterpret_cast<const float4*>(xr + (c + 1) * 32 + fq * 4);
    unsigned char* base = xsraw + bf * 8192;
#pragma unroll
    for (int ff = 0; ff < 4; ++ff) {
      int f = fq * 4 + ff;
      float av = (&v0.x)[ff], bv = (&v1.x)[ff];
      unsigned short ah = f2bf(av), bh_ = f2bf(bv);
      unsigned short al = f2bf(av - bf2f(ah)), bl_ = f2bf(bv - bf2f(bh_));
      int bo = ((f << 7) + (c << 1)) ^ ((f & 7) << 4);
      *reinterpret_cast<unsigned int*>(base + bo) =
          (unsigned int)ah | ((unsigned int)bh_ << 16);
      *reinterpret_cast<unsigned int*>(base + 4096 + bo) =
          (unsigned int)al | ((unsigned int)bl_ << 16);
    }
  };

  stage(0, 0);
  __syncthreads();
  for (int r = 0; r < 8; ++r) {
    if (r < 7) stage(r + 1, (r + 1) & 1);
    const unsigned char* bufb = xsraw + (r & 1) * 8192;
    f32x4 acc[2][2];
#pragma unroll
    for (int ft = 0; ft < 2; ++ft)
#pragma unroll
      for (int t2 = 0; t2 < 2; ++t2) {
        f32x4 z = {0.f, 0.f, 0.f, 0.f};
        acc[ft][t2] = z;
      }
#pragma unroll
    for (int kc = 0; kc < 6; ++kc) {
#pragma unroll
      for (int ft = 0; ft < 2; ++ft) {
        short8 ah = *reinterpret_cast<const short8*>(bufb + offs[ft][kc]);
        short8 al = *reinterpret_cast<const short8*>(bufb + 4096 + offs[ft][kc]);
        acc[ft][0] = __builtin_amdgcn_mfma_f32_16x16x32_bf16(ah, bh[kc][0], acc[ft][0], 0, 0, 0);
        acc[ft][1] = __builtin_amdgcn_mfma_f32_16x16x32_bf16(ah, bh[kc][1], acc[ft][1], 0, 0, 0);
        acc[ft][0] = __builtin_amdgcn_mfma_f32_16x16x32_bf16(ah, bl[kc][0], acc[ft][0], 0, 0, 0);
        acc[ft][1] = __builtin_amdgcn_mfma_f32_16x16x32_bf16(ah, bl[kc][1], acc[ft][1], 0, 0, 0);
        acc[ft][0] = __builtin_amdgcn_mfma_f32_16x16x32_bf16(al, bh[kc][0], acc[ft][0], 0, 0, 0);
        acc[ft][1] = __builtin_amdgcn_mfma_f32_16x16x32_bf16(al, bh[kc][1], acc[ft][1], 0, 0, 0);
      }
    }
    const int s = s0 + r;
    const float ju = jsu[s], jv = jsv[s];
    float* hrow = h1s + (size_t)s * 4096;
#pragma unroll
    for (int ft = 0; ft < 2; ++ft)
#pragma unroll
      for (int t2 = 0; t2 < 2; ++t2) {
        int f_base = ft * 16 + ((lane >> 4) << 2);
        int o_out = (wv * 2 + t2) * 16 + (lane & 15);
        float4 hv;
#pragma unroll
        for (int reg = 0; reg < 4; ++reg) {
          float val = acc[ft][t2][reg] + biasv[t2];
          (&hv.x)[reg] = val;
          Uacc[ft][t2][reg] += ju * val;
          Vacc[ft][t2][reg] += jv * val;
        }
        *reinterpret_cast<float4*>(hrow + o_out * 32 + f_base) = hv;
      }
    __syncthreads();
  }
  const int g = blockIdx.x >> 4;  // global segment (b*8+seg), 16 blocks/segment
  float* su = segsum + (size_t)g * 2 * 4096;
#pragma unroll
  for (int ft = 0; ft < 2; ++ft)
#pragma unroll
    for (int t2 = 0; t2 < 2; ++t2)
#pragma unroll
      for (int reg = 0; reg < 4; ++reg) {
        int col = ((wv * 2 + t2) * 16 + (lane & 15)) * 32 + ft * 16 +
                  ((lane >> 4) << 2) + reg;
        atomicAdd(su + col, Uacc[ft][t2][reg]);
        atomicAdd(su + 4096 + col, Vacc[ft][t2][reg]);
      }
}

// ---------------- pass2: segment-parallel streaming sweep + emit -------------
__global__ __launch_bounds__(128) void pass2_kernel(
    const float* __restrict__ h1s, const float* __restrict__ segsum,
    const float* __restrict__ jsu, const float* __restrict__ jsv,
    const int* __restrict__ isrow, const int* __restrict__ isk,
    const float* __restrict__ isep, const float* __restrict__ isea,
    float* __restrict__ out) {
  const int tid = threadIdx.x;
  const int chunk = blockIdx.x & 31, gseg = blockIdx.x >> 5;
  const int b = gseg >> 3, seg = gseg & 7;
  const int col = chunk * 128 + tid;
  __shared__ int kL[1024];
  __shared__ float epL[1024];
  __shared__ float eaL[1024];
  __shared__ int rowL[1024];
  __shared__ float juL[128];
  __shared__ float jvL[128];
  for (int i = tid; i < 1024; i += 128) {
    kL[i] = isk[b * 1024 + i];
    epL[i] = isep[b * 1024 + i];
    eaL[i] = isea[b * 1024 + i];
    rowL[i] = isrow[b * 1024 + i];
  }
  juL[tid] = jsu[b * 1024 + seg * 128 + tid];
  jvL[tid] = jsv[b * 1024 + seg * 128 + tid];
  float U = 0.f, V = 0.f, Utot = 0.f;
#pragma unroll
  for (int s8 = 0; s8 < 8; ++s8) {
    float uu = segsum[((size_t)(b * 8 + s8) * 2) * 4096 + col];
    float vv = segsum[((size_t)(b * 8 + s8) * 2 + 1) * 4096 + col];
    Utot += uu;
    if (s8 < seg) { U += uu; V += vv; }
  }
  __syncthreads();
  int ip, ip1;
  {
    int lo = 0, hi = 1024, thr = seg * 128;
    while (lo < hi) { int mid = (lo + hi) >> 1; if (kL[mid] < thr) lo = mid + 1; else hi = mid; }
    ip = lo;
  }
  if (seg == 7) ip1 = 1024;
  else {
    int lo = ip, hi = 1024, thr = seg * 128 + 128;
    while (lo < hi) { int mid = (lo + hi) >> 1; if (kL[mid] < thr) lo = mid + 1; else hi = mid; }
    ip1 = lo;
  }
  const float* hrow = h1s + ((size_t)(b * 1024 + seg * 128)) * 4096 + col;
  for (int t = 0; t < 128; t += 16) {
    float rr[16];
#pragma unroll
    for (int q = 0; q < 16; ++q) rr[q] = hrow[(size_t)(t + q) * 4096];
#pragma unroll
    for (int q = 0; q < 16; ++q) {
      int cnt = seg * 128 + t + q;
      while (ip < ip1 && kL[ip] <= cnt) {
        out[(size_t)rowL[ip] * 4096 + col] = epL[ip] * (Utot - U) + eaL[ip] * V;
        ++ip;
      }
      U += juL[t + q] * rr[q];
      V += jvL[t + q] * rr[q];
    }
  }
  while (ip < ip1) {
    out[(size_t)rowL[ip] * 4096 + col] = epL[ip] * (Utot - U) + eaL[ip] * V;
    ++ip;
  }
}

extern "C" void kernel_launch(void* const* d_in, const int* in_sizes, int n_in,
                              void* d_out, int out_size, void* d_ws, size_t ws_size,
                              hipStream_t stream) {
  const float* x     = (const float*)d_in[0];
  const float* n     = (const float*)d_in[1];
  const float* w     = (const float*)d_in[2];
  const float* bias  = (const float*)d_in[3];
  const float* att1w = (const float*)d_in[4];
  const float* att2w = (const float*)d_in[5];
  float* out = (float*)d_out;
  float* wsf = (float*)d_ws;

  size_t off = 0;
  float* h1s  = wsf + off; off += (size_t)Mm * Dd;  // 128 MB, sorted-j order
  float* W1   = wsf + off; off += 2048;
  float* W2   = wsf + off; off += 2048;
  float* c12  = wsf + off; off += 64;
  float* a1v  = wsf + off; off += Mm;
  float* a2v  = wsf + off; off += Mm;
  float* jsu  = wsf + off; off += Mm;
  float* jsv  = wsf + off; off += Mm;
  int*   jrow = (int*)(wsf + off); off += Mm;
  int*   isrow= (int*)(wsf + off); off += Mm;
  int*   isk  = (int*)(wsf + off); off += Mm;
  float* isep = wsf + off; off += Mm;
  float* isea = wsf + off; off += Mm;
  float* segsum = wsf + off; off += (size_t)64 * 2 * 4096;  // 2 MB
  unsigned short* Bph = (unsigned short*)(wsf + off); off += 12288;
  unsigned short* Bpl = (unsigned short*)(wsf + off); off += 12288;
  // total ~130.4 MB

  prep_kernel<<<64, 256, 0, stream>>>(w, bias, att1w, att2w, Bph, Bpl, W1, W2, c12);
  a12_kernel<<<1024, 256, 0, stream>>>(x, n, W1, W2, c12, a1v, a2v, segsum);
  sortprep_kernel<<<Bb, 1024, 0, stream>>>(a1v, a2v, jsu, jsv, jrow,
                                           isrow, isk, isep, isea);
  conv_kernel<<<Mm / 8, 256, 0, stream>>>(x, Bph, Bpl, bias, jrow, jsu, jsv,
                                          h1s, segsum);
  pass2_kernel<<<2048, 128, 0, stream>>>(h1s, segsum, jsu, jsv,
                                         isrow, isk, isep, isea, out);
}